// Round 8
// baseline (146.450 us; speedup 1.0000x reference)
//
#include <hip/hip_runtime.h>
#include <hip/hip_bf16.h>

typedef __bf16 bf16x8_t __attribute__((ext_vector_type(8)));
typedef float f32x4_t __attribute__((ext_vector_type(4)));
using bf16 = __hip_bfloat16;

#define ASG __attribute__((address_space(1)))
#define ASL __attribute__((address_space(3)))

__device__ __forceinline__ void gld_lds16(const void* g, void* l) {
  // lane i of the wave lands at (wave-uniform lds base) + i*16 bytes; src is per-lane.
  __builtin_amdgcn_global_load_lds((ASG void*)const_cast<void*>(g),
                                   (ASL void*)l, 16, 0, 0);
}

__device__ __forceinline__ unsigned short f2bf_bits(float v) {
  __hip_bfloat16 h = __float2bfloat16(v);
  return *reinterpret_cast<unsigned short*>(&h);
}

// mish(x) = x*tanh(softplus(x)) = x*n/(n+2) with n = e^x*(e^x+2).
__device__ __forceinline__ float mish_f(float x) {
  float z = __expf(x);
  float n = z * (z + 2.0f);
  float m = x * n / (n + 2.0f);
  return (x > 10.0f) ? x : m;
}

// 13 cubic B-spline basis values (grid 10, k=3, [-2,2]) + mish -> 28B LDS region.
__device__ __forceinline__ void kan_feats28(bf16* dst, float x) {
  unsigned int* d32 = (unsigned int*)dst;
#pragma unroll
  for (int d = 0; d < 7; ++d) d32[d] = 0u;
  float t = (x + 3.2f) * 2.5f;
  if (t >= 0.0f && t < 16.0f) {
    float tf = floorf(t);
    int c = (int)tf;
    float u = t - tf;
    float um = 1.0f - u;
    float u2 = u * u, u3 = u2 * u;
    const float s6 = 1.0f / 6.0f;
    float w0 = um * um * um * s6;
    float w1 = (3.0f * u3 - 6.0f * u2 + 4.0f) * s6;
    float w2 = (-3.0f * u3 + 3.0f * u2 + 3.0f * u + 1.0f) * s6;
    float w3 = u3 * s6;
    int j0 = c - 3;
    if (j0 >= 0)               dst[j0]     = __float2bfloat16(w0);
    if (j0 >= -1 && j0 <= 11)  dst[j0 + 1] = __float2bfloat16(w1);
    if (j0 >= -2 && j0 <= 10)  dst[j0 + 2] = __float2bfloat16(w2);
    if (j0 <= 9)               dst[j0 + 3] = __float2bfloat16(w3);
  }
  dst[13] = __float2bfloat16(mish_f(x));
}

// Builds W1t (row-major K=704), W2f + W3f (MFMA-fragment-major).
// Frag-major: frag s covers k=s*32..+31 for 16 N-rows; element (n,quad,el) at
// s*512 + n*32 + quad*8 + el. k'=i*14+2d is even -> pair dwords stay in-slot.
__global__ __launch_bounds__(256) void prep_all(
    const float* __restrict__ c1, const float* __restrict__ sb1, const float* __restrict__ sp1,
    const float* __restrict__ c2, const float* __restrict__ sb2, const float* __restrict__ sp2,
    const float* __restrict__ c3, const float* __restrict__ sb3, const float* __restrict__ sp3,
    bf16* __restrict__ W1t, bf16* __restrict__ W2f, bf16* __restrict__ W3f) {
  const int b = blockIdx.x, o = threadIdx.x;
  float vals[14];
  if (b < 49) {
    const int i = b;
    const size_t io = (size_t)i * 256 + o;
    const float spv = sp1[io];
#pragma unroll
    for (int r = 0; r < 13; ++r) vals[r] = c1[io * 13 + r] * spv;
    vals[13] = sb1[io];
    unsigned int* dst = (unsigned int*)(W1t + (size_t)o * 704 + i * 14);
#pragma unroll
    for (int d = 0; d < 7; ++d)
      dst[d] = (unsigned int)f2bf_bits(vals[2 * d]) |
               ((unsigned int)f2bf_bits(vals[2 * d + 1]) << 16);
  } else if (b == 49) {
    unsigned int* dst = (unsigned int*)(W1t + (size_t)o * 704 + 686);
#pragma unroll
    for (int d = 0; d < 9; ++d) dst[d] = 0u;  // K-pad 686..703
  } else if (b < 306) {
    const int i = b - 50;
    const size_t io = (size_t)i * 256 + o;
    const float spv = sp2[io];
#pragma unroll
    for (int r = 0; r < 13; ++r) vals[r] = c2[io * 13 + r] * spv;
    vals[13] = sb2[io];
    const int ntg = o >> 4, lr = o & 15;
#pragma unroll
    for (int d = 0; d < 7; ++d) {
      const int k2 = i * 14 + 2 * d;
      const int kc = k2 / 224, rem = k2 % 224;
      const int ks = rem / 32, r2 = rem % 32, quad = r2 / 8, el = r2 % 8;
      const size_t off = ((size_t)((kc * 7 + ks) * 16 + ntg)) * 512 + lr * 32 + quad * 8 + el;
      *(unsigned int*)(W2f + off) = (unsigned int)f2bf_bits(vals[2 * d]) |
                                    ((unsigned int)f2bf_bits(vals[2 * d + 1]) << 16);
    }
  } else {
    const int i = b - 306;
    if (o < 10) {
      const size_t io = (size_t)i * 10 + o;
      const float spv = sp3[io];
#pragma unroll
      for (int r = 0; r < 13; ++r) vals[r] = c3[io * 13 + r] * spv;
      vals[13] = sb3[io];
#pragma unroll
      for (int d = 0; d < 7; ++d) {
        const int k2 = i * 14 + 2 * d;
        const int s = k2 >> 5, r2 = k2 & 31;
        const size_t off = (size_t)s * 512 + o * 32 + (r2 >> 3) * 8 + (r2 & 7);
        *(unsigned int*)(W3f + off) = (unsigned int)f2bf_bits(vals[2 * d]) |
                                      ((unsigned int)f2bf_bits(vals[2 * d + 1]) << 16);
      }
    } else if (o < 16) {
#pragma unroll
      for (int d = 0; d < 7; ++d) {
        const int k2 = i * 14 + 2 * d;
        const int s = k2 >> 5, r2 = k2 & 31;
        *(unsigned int*)(W3f + (size_t)s * 512 + o * 32 + (r2 >> 3) * 8 + (r2 & 7)) = 0u;
      }
    }
  }
}

// 4 images per block: 4x4 avg-pool 28x28 -> 49, basis+mish -> A1 rows (704 bf16).
__global__ __launch_bounds__(256) void pool_basis1(const float* __restrict__ x,
                                                   bf16* __restrict__ A1) {
  __shared__ __align__(16) float xs[3136];
  __shared__ __align__(16) bf16 arow[4 * 704];
  const int b4 = blockIdx.x * 4, t = threadIdx.x;
  const float4* xsrc = (const float4*)(x + (size_t)b4 * 784);
  float4* xd = (float4*)xs;
#pragma unroll
  for (int l = t; l < 784; l += 256) xd[l] = xsrc[l];
  __syncthreads();
  if (t < 196) {
    const int img = t / 49, p = t - img * 49;
    const int oh = p / 7, ow = p - oh * 7;
    const float* xi = xs + img * 784;
    float s = 0.f;
#pragma unroll
    for (int r = 0; r < 4; ++r)
#pragma unroll
      for (int c = 0; c < 4; ++c) s += xi[(oh * 4 + r) * 28 + ow * 4 + c];
    kan_feats28(&arow[img * 704 + p * 14], s * (1.0f / 16.0f));
  } else if (t < 232) {
    const int q = t - 196;  // 36 threads zero 4 pads of 9 dwords
    const int img = q / 9, d = q - img * 9;
    ((unsigned int*)(arow + img * 704 + 686))[d] = 0u;
  }
  __syncthreads();
  uint4* dst = (uint4*)(A1 + (size_t)b4 * 704);
  const uint4* src = (const uint4*)arow;
#pragma unroll
  for (int l = t; l < 352; l += 256) dst[l] = src[l];
}

// Layer-1 GEMM (K=704, BK=64, XOR-swizzled LDS), bias added.
__global__ __launch_bounds__(256) void gemm1s(
    const bf16* __restrict__ A, const bf16* __restrict__ Wt,
    const float* __restrict__ bias, float* __restrict__ H) {
  constexpr int K = 704;
  __shared__ __align__(16) bf16 As[64 * 64];
  __shared__ __align__(16) bf16 Bs[64 * 64];
  const int t = threadIdx.x;
  const int wv = t >> 6, lane = t & 63, quad = lane >> 4, lr = lane & 15;
  const int n0 = blockIdx.x * 64;
  const int m0 = blockIdx.y * 64;
  const int srow0 = lane >> 3;
  const int cg = (lane & 7) ^ srow0;
  const bf16* gA0 = A + (size_t)(m0 + 8 * wv + srow0) * K + cg * 8;
  const bf16* gA1 = A + (size_t)(m0 + 32 + 8 * wv + srow0) * K + cg * 8;
  const bf16* gB0 = Wt + (size_t)(n0 + 8 * wv + srow0) * K + cg * 8;
  const bf16* gB1 = Wt + (size_t)(n0 + 32 + 8 * wv + srow0) * K + cg * 8;
  char* const lA = (char*)As + wv * 1024;
  char* const lB = (char*)Bs + wv * 1024;
  const int wm = (wv & 1) * 32, wn = (wv >> 1) * 32;
  const int swz = lr & 7;
  f32x4_t acc00 = {0.f, 0.f, 0.f, 0.f}, acc01 = acc00, acc10 = acc00, acc11 = acc00;
  for (int k0 = 0; k0 < K; k0 += 64) {
    gld_lds16(gA0 + k0, lA);
    gld_lds16(gA1 + k0, lA + 4096);
    gld_lds16(gB0 + k0, lB);
    gld_lds16(gB1 + k0, lB + 4096);
    __syncthreads();
#pragma unroll
    for (int s = 0; s < 2; ++s) {
      const int co = ((s * 4 + quad) ^ swz) * 16;
      bf16x8_t a0 = *(const bf16x8_t*)((char*)As + (wm + lr) * 128 + co);
      bf16x8_t a1 = *(const bf16x8_t*)((char*)As + (wm + 16 + lr) * 128 + co);
      bf16x8_t b0 = *(const bf16x8_t*)((char*)Bs + (wn + lr) * 128 + co);
      bf16x8_t b1 = *(const bf16x8_t*)((char*)Bs + (wn + 16 + lr) * 128 + co);
      acc00 = __builtin_amdgcn_mfma_f32_16x16x32_bf16(a0, b0, acc00, 0, 0, 0);
      acc01 = __builtin_amdgcn_mfma_f32_16x16x32_bf16(a0, b1, acc01, 0, 0, 0);
      acc10 = __builtin_amdgcn_mfma_f32_16x16x32_bf16(a1, b0, acc10, 0, 0, 0);
      acc11 = __builtin_amdgcn_mfma_f32_16x16x32_bf16(a1, b1, acc11, 0, 0, 0);
    }
    __syncthreads();
  }
  const int cb = n0 + wn + lr;
  const float bn0 = bias[cb], bn1 = bias[cb + 16];
#pragma unroll
  for (int r = 0; r < 4; ++r) {
    const size_t row = (size_t)(m0 + wm + quad * 4 + r);
    H[row * 256 + cb] = acc00[r] + bn0;
    H[row * 256 + cb + 16] = acc01[r] + bn1;
    H[(row + 16) * 256 + cb] = acc10[r] + bn0;
    H[(row + 16) * 256 + cb + 16] = acc11[r] + bn1;
  }
}

// Fused KAN layer 2, v5: 512-thr blocks, grid (128 m, 4 z) = 512 blocks.
// Wave w owns cols w*32..+31 (acc 4x2 frags = 32 VGPRs). Feats once globally,
// dbuf LDS, one barrier/chunk. B frags register-direct from frag-major W2f
// with a 4-deep circular prefetch queue (4x14 MFMA in flight per load > L2
// latency). Partials to Hp[z].
__global__ __launch_bounds__(512, 4) void kan_gemm2(
    const float* __restrict__ Hin, const bf16* __restrict__ W2f,
    float* __restrict__ Hp) {
  __shared__ __align__(16) bf16 As[2][64 * 232];  // 2 x 29696 B
  const int t = threadIdx.x;
  const int w = t >> 6, lane = t & 63, quad = lane >> 4, lr = lane & 15;
  const int m0 = blockIdx.x * 64;
  const int z = blockIdx.y;
  const int ej = t & 15, er0 = (t >> 4) & 31;
  const int foff = lr * 32 + quad * 8;
  f32x4_t acc[4][2];
#pragma unroll
  for (int m = 0; m < 4; ++m) {
    acc[m][0] = (f32x4_t){0.f, 0.f, 0.f, 0.f};
    acc[m][1] = (f32x4_t){0.f, 0.f, 0.f, 0.f};
  }
  const float* hp = Hin + (size_t)(m0 + er0) * 256 + z * 64 + ej;
  // feats for chunk 0
  kan_feats28(As[0] + er0 * 232 + ej * 14, hp[0]);
  kan_feats28(As[0] + (er0 + 32) * 232 + ej * 14, hp[32 * 256]);
  // B prefetch queue: frag-pair stride per K-step = 16 frags = 8192 elements
  const bf16* wbase = W2f + ((size_t)(z * 28 * 16 + w * 2)) * 512 + foff;
  bf16x8_t p0[4], p1[4];
#pragma unroll
  for (int s = 0; s < 4; ++s) {
    p0[s] = *(const bf16x8_t*)(wbase + (size_t)s * 8192);
    p1[s] = *(const bf16x8_t*)(wbase + (size_t)s * 8192 + 512);
  }
#pragma unroll
  for (int kcl = 0; kcl < 4; ++kcl) {
    __syncthreads();
    const bf16* cur = As[kcl & 1];
    bf16* nxt = As[(kcl & 1) ^ 1];
#pragma unroll
    for (int ks = 0; ks < 7; ++ks) {
      const int step = kcl * 7 + ks;
      const int slot = step & 3;
      bf16x8_t b0 = p0[slot], b1 = p1[slot];
      if (step + 4 < 28) {
        p0[slot] = *(const bf16x8_t*)(wbase + (size_t)(step + 4) * 8192);
        p1[slot] = *(const bf16x8_t*)(wbase + (size_t)(step + 4) * 8192 + 512);
      }
#pragma unroll
      for (int m = 0; m < 4; ++m) {
        bf16x8_t a = *(const bf16x8_t*)(cur + (m * 16 + lr) * 232 + ks * 32 + quad * 8);
        acc[m][0] = __builtin_amdgcn_mfma_f32_16x16x32_bf16(a, b0, acc[m][0], 0, 0, 0);
        acc[m][1] = __builtin_amdgcn_mfma_f32_16x16x32_bf16(a, b1, acc[m][1], 0, 0, 0);
      }
    }
    if (kcl < 3) {
      kan_feats28(nxt + er0 * 232 + ej * 14, hp[(kcl + 1) * 16]);
      kan_feats28(nxt + (er0 + 32) * 232 + ej * 14, hp[32 * 256 + (kcl + 1) * 16]);
    }
  }
  float* Hpz = Hp + (size_t)z * (8192 * 256);
  const int c0 = w * 32 + lr;
#pragma unroll
  for (int m = 0; m < 4; ++m)
#pragma unroll
    for (int r = 0; r < 4; ++r) {
      const size_t row = (size_t)(m0 + m * 16 + quad * 4 + r);
      Hpz[row * 256 + c0] = acc[m][0][r];
      Hpz[row * 256 + c0 + 16] = acc[m][1][r];
    }
}

// Fused layer 3, v2: reduces the 4 layer-2 partials (+b2) inline, B fragments
// register-direct from frag-major W3f (114KB, L2-resident broadcast). No B
// staging, 3 barriers, split-K z=8 -> 1024 blocks (4/CU). Wave wv owns rows
// wv*16..+15; all waves share the 16 output cols (10 real).
__global__ __launch_bounds__(256) void kan_gemm3(
    const float* __restrict__ Hp, const float* __restrict__ b2,
    const bf16* __restrict__ W3f, float* __restrict__ part) {
  __shared__ __align__(16) bf16 As[64 * 232];
  const int t = threadIdx.x;
  const int wv = t >> 6, lane = t & 63, quad = lane >> 4, lr = lane & 15;
  const int m0 = blockIdx.x * 64;
  const int z = blockIdx.y;  // 0..7
  const int ej = t & 15, er0 = t >> 4;
  const int foff = lr * 32 + quad * 8;
  f32x4_t acc = {0.f, 0.f, 0.f, 0.f};
#pragma unroll
  for (int kcl = 0; kcl < 2; ++kcl) {
    const int kc = z * 2 + kcl;
    const float bc = b2[kc * 16 + ej];
    const float* hp = Hp + (size_t)(m0 + er0) * 256 + kc * 16 + ej;
    if (kcl) __syncthreads();  // all waves done reading As before overwrite
#pragma unroll
    for (int e = 0; e < 4; ++e) {
      const size_t idx = (size_t)e * 16 * 256;
      float h = hp[idx] + hp[idx + 2097152] + hp[idx + 4194304] + hp[idx + 6291456] + bc;
      kan_feats28(As + (er0 + 16 * e) * 232 + ej * 14, h);
    }
    __syncthreads();
#pragma unroll
    for (int ks = 0; ks < 7; ++ks) {
      bf16x8_t b = *(const bf16x8_t*)(W3f + (size_t)(kc * 7 + ks) * 512 + foff);
      bf16x8_t a = *(const bf16x8_t*)(As + (wv * 16 + lr) * 232 + ks * 32 + quad * 8);
      acc = __builtin_amdgcn_mfma_f32_16x16x32_bf16(a, b, acc, 0, 0, 0);
    }
  }
#pragma unroll
  for (int r = 0; r < 4; ++r)
    part[(size_t)z * 131072 + (size_t)lr * 8192 + (m0 + wv * 16 + quad * 4 + r)] = acc[r];
}

// Reduce 8 split-K partials + bias, log_softmax over 10 classes.
__global__ __launch_bounds__(256) void lsm(const float* __restrict__ part,
                                           const float* __restrict__ b3,
                                           float* __restrict__ out) {
  const int row = blockIdx.x * 256 + threadIdx.x;
  float v[10];
#pragma unroll
  for (int o = 0; o < 10; ++o) {
    float s = b3[o];
#pragma unroll
    for (int kc = 0; kc < 8; ++kc) s += part[(size_t)kc * 131072 + (size_t)o * 8192 + row];
    v[o] = s;
  }
  float m = v[0];
#pragma unroll
  for (int o = 1; o < 10; ++o) m = fmaxf(m, v[o]);
  float se = 0.f;
#pragma unroll
  for (int o = 0; o < 10; ++o) se += expf(v[o] - m);
  const float l = m + logf(se);
#pragma unroll
  for (int o = 0; o < 10; ++o) out[(size_t)row * 10 + o] = v[o] - l;
}

extern "C" void kernel_launch(void* const* d_in, const int* in_sizes, int n_in,
                              void* d_out, int out_size, void* d_ws, size_t ws_size,
                              hipStream_t stream) {
  const float* x = (const float*)d_in[0];
  const float* coef1 = (const float*)d_in[1];
  const float* sb1 = (const float*)d_in[2];
  const float* sp1 = (const float*)d_in[3];
  const float* b1 = (const float*)d_in[4];
  const float* coef2 = (const float*)d_in[5];
  const float* sb2 = (const float*)d_in[6];
  const float* sp2 = (const float*)d_in[7];
  const float* b2 = (const float*)d_in[8];
  const float* coef3 = (const float*)d_in[9];
  const float* sb3 = (const float*)d_in[10];
  const float* sp3 = (const float*)d_in[11];
  const float* b3 = (const float*)d_in[12];
  float* out = (float*)d_out;

  char* ws = (char*)d_ws;
  size_t off = 0;
  bf16* A1 = (bf16*)(ws + off);    off += 11534336;  // 8192*704*2
  bf16* W1t = (bf16*)(ws + off);   off += 360448;    // 256*704*2
  bf16* W2f = (bf16*)(ws + off);   off += 1835008;   // 256*3584*2 (frag-major)
  bf16* W3f = (bf16*)(ws + off);   off += 114688;    // 16*3584*2 (frag-major)
  float* H1 = (float*)(ws + off);  off += 8388608;   // 8192*256*4
  float* Hp = (float*)(ws + off);  off += 33554432;  // 4 x 8192*256*4
  float* part = (float*)(ws + off); off += 4194304;  // 8*16*8192*4

  prep_all<<<562, 256, 0, stream>>>(coef1, sb1, sp1, coef2, sb2, sp2,
                                    coef3, sb3, sp3, W1t, W2f, W3f);
  pool_basis1<<<2048, 256, 0, stream>>>(x, A1);
  gemm1s<<<dim3(4, 128), 256, 0, stream>>>(A1, W1t, b1, H1);
  kan_gemm2<<<dim3(128, 4), 512, 0, stream>>>(H1, W2f, Hp);
  kan_gemm3<<<dim3(128, 8), 256, 0, stream>>>(Hp, b2, W3f, part);
  lsm<<<32, 256, 0, stream>>>(part, b3, out);
}

// Round 9
// 145.698 us; speedup vs baseline: 1.0052x; 1.0052x over previous
//
#include <hip/hip_runtime.h>
#include <hip/hip_bf16.h>

typedef __bf16 bf16x8_t __attribute__((ext_vector_type(8)));
typedef float f32x4_t __attribute__((ext_vector_type(4)));
using bf16 = __hip_bfloat16;

#define ASG __attribute__((address_space(1)))
#define ASL __attribute__((address_space(3)))

__device__ __forceinline__ void gld_lds16(const void* g, void* l) {
  // lane i of the wave lands at (wave-uniform lds base) + i*16 bytes; src is per-lane.
  __builtin_amdgcn_global_load_lds((ASG void*)const_cast<void*>(g),
                                   (ASL void*)l, 16, 0, 0);
}

__device__ __forceinline__ unsigned short f2bf_bits(float v) {
  __hip_bfloat16 h = __float2bfloat16(v);
  return *reinterpret_cast<unsigned short*>(&h);
}

// mish(x) = x*tanh(softplus(x)) = x*n/(n+2) with n = e^x*(e^x+2).
__device__ __forceinline__ float mish_f(float x) {
  float z = __expf(x);
  float n = z * (z + 2.0f);
  float m = x * n / (n + 2.0f);
  return (x > 10.0f) ? x : m;
}

// 13 cubic B-spline basis values (grid 10, k=3, [-2,2]) + mish -> 28B LDS region.
__device__ __forceinline__ void kan_feats28(bf16* dst, float x) {
  unsigned int* d32 = (unsigned int*)dst;
#pragma unroll
  for (int d = 0; d < 7; ++d) d32[d] = 0u;
  float t = (x + 3.2f) * 2.5f;
  if (t >= 0.0f && t < 16.0f) {
    float tf = floorf(t);
    int c = (int)tf;
    float u = t - tf;
    float um = 1.0f - u;
    float u2 = u * u, u3 = u2 * u;
    const float s6 = 1.0f / 6.0f;
    float w0 = um * um * um * s6;
    float w1 = (3.0f * u3 - 6.0f * u2 + 4.0f) * s6;
    float w2 = (-3.0f * u3 + 3.0f * u2 + 3.0f * u + 1.0f) * s6;
    float w3 = u3 * s6;
    int j0 = c - 3;
    if (j0 >= 0)               dst[j0]     = __float2bfloat16(w0);
    if (j0 >= -1 && j0 <= 11)  dst[j0 + 1] = __float2bfloat16(w1);
    if (j0 >= -2 && j0 <= 10)  dst[j0 + 2] = __float2bfloat16(w2);
    if (j0 <= 9)               dst[j0 + 3] = __float2bfloat16(w3);
  }
  dst[13] = __float2bfloat16(mish_f(x));
}

// Fused: blocks 0..2047 pool+basis (4 images each); 2048..2609 build weights.
// W1t row-major K=704; W2f/W3f MFMA-fragment-major (frag s: 16 rows x 32 k,
// element (n,quad,el) at s*512 + n*32 + quad*8 + el; k'=i*14+2d even -> dwords).
__global__ __launch_bounds__(256) void prep_pool(
    const float* __restrict__ x,
    const float* __restrict__ c1, const float* __restrict__ sb1, const float* __restrict__ sp1,
    const float* __restrict__ c2, const float* __restrict__ sb2, const float* __restrict__ sp2,
    const float* __restrict__ c3, const float* __restrict__ sb3, const float* __restrict__ sp3,
    bf16* __restrict__ A1, bf16* __restrict__ W1t, bf16* __restrict__ W2f,
    bf16* __restrict__ W3f) {
  if (blockIdx.x < 2048) {
    __shared__ __align__(16) float xs[3136];
    __shared__ __align__(16) bf16 arow[4 * 704];
    const int b4 = blockIdx.x * 4, t = threadIdx.x;
    const float4* xsrc = (const float4*)(x + (size_t)b4 * 784);
    float4* xd = (float4*)xs;
#pragma unroll
    for (int l = t; l < 784; l += 256) xd[l] = xsrc[l];
    __syncthreads();
    if (t < 196) {
      const int img = t / 49, p = t - img * 49;
      const int oh = p / 7, ow = p - oh * 7;
      const float* xi = xs + img * 784;
      float s = 0.f;
#pragma unroll
      for (int r = 0; r < 4; ++r)
#pragma unroll
        for (int c = 0; c < 4; ++c) s += xi[(oh * 4 + r) * 28 + ow * 4 + c];
      kan_feats28(&arow[img * 704 + p * 14], s * (1.0f / 16.0f));
    } else if (t < 232) {
      const int q = t - 196;  // 36 threads zero 4 pads of 9 dwords
      const int img = q / 9, d = q - img * 9;
      ((unsigned int*)(arow + img * 704 + 686))[d] = 0u;
    }
    __syncthreads();
    uint4* dst = (uint4*)(A1 + (size_t)b4 * 704);
    const uint4* src = (const uint4*)arow;
#pragma unroll
    for (int l = t; l < 352; l += 256) dst[l] = src[l];
    return;
  }
  const int b = blockIdx.x - 2048, o = threadIdx.x;
  float vals[14];
  if (b < 49) {
    const int i = b;
    const size_t io = (size_t)i * 256 + o;
    const float spv = sp1[io];
#pragma unroll
    for (int r = 0; r < 13; ++r) vals[r] = c1[io * 13 + r] * spv;
    vals[13] = sb1[io];
    unsigned int* dst = (unsigned int*)(W1t + (size_t)o * 704 + i * 14);
#pragma unroll
    for (int d = 0; d < 7; ++d)
      dst[d] = (unsigned int)f2bf_bits(vals[2 * d]) |
               ((unsigned int)f2bf_bits(vals[2 * d + 1]) << 16);
  } else if (b == 49) {
    unsigned int* dst = (unsigned int*)(W1t + (size_t)o * 704 + 686);
#pragma unroll
    for (int d = 0; d < 9; ++d) dst[d] = 0u;  // K-pad 686..703
  } else if (b < 306) {
    const int i = b - 50;
    const size_t io = (size_t)i * 256 + o;
    const float spv = sp2[io];
#pragma unroll
    for (int r = 0; r < 13; ++r) vals[r] = c2[io * 13 + r] * spv;
    vals[13] = sb2[io];
    const int ntg = o >> 4, lr = o & 15;
#pragma unroll
    for (int d = 0; d < 7; ++d) {
      const int k2 = i * 14 + 2 * d;
      const int kc = k2 / 224, rem = k2 % 224;
      const int ks = rem / 32, r2 = rem % 32, quad = r2 / 8, el = r2 % 8;
      const size_t off = ((size_t)((kc * 7 + ks) * 16 + ntg)) * 512 + lr * 32 + quad * 8 + el;
      *(unsigned int*)(W2f + off) = (unsigned int)f2bf_bits(vals[2 * d]) |
                                    ((unsigned int)f2bf_bits(vals[2 * d + 1]) << 16);
    }
  } else {
    const int i = b - 306;
    if (o < 10) {
      const size_t io = (size_t)i * 10 + o;
      const float spv = sp3[io];
#pragma unroll
      for (int r = 0; r < 13; ++r) vals[r] = c3[io * 13 + r] * spv;
      vals[13] = sb3[io];
#pragma unroll
      for (int d = 0; d < 7; ++d) {
        const int k2 = i * 14 + 2 * d;
        const int s = k2 >> 5, r2 = k2 & 31;
        const size_t off = (size_t)s * 512 + o * 32 + (r2 >> 3) * 8 + (r2 & 7);
        *(unsigned int*)(W3f + off) = (unsigned int)f2bf_bits(vals[2 * d]) |
                                      ((unsigned int)f2bf_bits(vals[2 * d + 1]) << 16);
      }
    } else if (o < 16) {
#pragma unroll
      for (int d = 0; d < 7; ++d) {
        const int k2 = i * 14 + 2 * d;
        const int s = k2 >> 5, r2 = k2 & 31;
        *(unsigned int*)(W3f + (size_t)s * 512 + o * 32 + (r2 >> 3) * 8 + (r2 & 7)) = 0u;
      }
    }
  }
}

// Layer-1 GEMM (K=704, BK=64, XOR-swizzled LDS), bias added.
__global__ __launch_bounds__(256) void gemm1s(
    const bf16* __restrict__ A, const bf16* __restrict__ Wt,
    const float* __restrict__ bias, float* __restrict__ H) {
  constexpr int K = 704;
  __shared__ __align__(16) bf16 As[64 * 64];
  __shared__ __align__(16) bf16 Bs[64 * 64];
  const int t = threadIdx.x;
  const int wv = t >> 6, lane = t & 63, quad = lane >> 4, lr = lane & 15;
  const int n0 = blockIdx.x * 64;
  const int m0 = blockIdx.y * 64;
  const int srow0 = lane >> 3;
  const int cg = (lane & 7) ^ srow0;
  const bf16* gA0 = A + (size_t)(m0 + 8 * wv + srow0) * K + cg * 8;
  const bf16* gA1 = A + (size_t)(m0 + 32 + 8 * wv + srow0) * K + cg * 8;
  const bf16* gB0 = Wt + (size_t)(n0 + 8 * wv + srow0) * K + cg * 8;
  const bf16* gB1 = Wt + (size_t)(n0 + 32 + 8 * wv + srow0) * K + cg * 8;
  char* const lA = (char*)As + wv * 1024;
  char* const lB = (char*)Bs + wv * 1024;
  const int wm = (wv & 1) * 32, wn = (wv >> 1) * 32;
  const int swz = lr & 7;
  f32x4_t acc00 = {0.f, 0.f, 0.f, 0.f}, acc01 = acc00, acc10 = acc00, acc11 = acc00;
  for (int k0 = 0; k0 < K; k0 += 64) {
    gld_lds16(gA0 + k0, lA);
    gld_lds16(gA1 + k0, lA + 4096);
    gld_lds16(gB0 + k0, lB);
    gld_lds16(gB1 + k0, lB + 4096);
    __syncthreads();
#pragma unroll
    for (int s = 0; s < 2; ++s) {
      const int co = ((s * 4 + quad) ^ swz) * 16;
      bf16x8_t a0 = *(const bf16x8_t*)((char*)As + (wm + lr) * 128 + co);
      bf16x8_t a1 = *(const bf16x8_t*)((char*)As + (wm + 16 + lr) * 128 + co);
      bf16x8_t b0 = *(const bf16x8_t*)((char*)Bs + (wn + lr) * 128 + co);
      bf16x8_t b1 = *(const bf16x8_t*)((char*)Bs + (wn + 16 + lr) * 128 + co);
      acc00 = __builtin_amdgcn_mfma_f32_16x16x32_bf16(a0, b0, acc00, 0, 0, 0);
      acc01 = __builtin_amdgcn_mfma_f32_16x16x32_bf16(a0, b1, acc01, 0, 0, 0);
      acc10 = __builtin_amdgcn_mfma_f32_16x16x32_bf16(a1, b0, acc10, 0, 0, 0);
      acc11 = __builtin_amdgcn_mfma_f32_16x16x32_bf16(a1, b1, acc11, 0, 0, 0);
    }
    __syncthreads();
  }
  const int cb = n0 + wn + lr;
  const float bn0 = bias[cb], bn1 = bias[cb + 16];
#pragma unroll
  for (int r = 0; r < 4; ++r) {
    const size_t row = (size_t)(m0 + wm + quad * 4 + r);
    H[row * 256 + cb] = acc00[r] + bn0;
    H[row * 256 + cb + 16] = acc01[r] + bn1;
    H[(row + 16) * 256 + cb] = acc10[r] + bn0;
    H[(row + 16) * 256 + cb + 16] = acc11[r] + bn1;
  }
}

// Fused KAN layer 2, v6: single-buffered feats LDS (29.7 KB) + launch_bounds
// (512,6): VGPR<=85, up to 3 blocks/CU = 24 waves/CU. Grid (128 m, 4 z).
// Wave w owns cols w*32..+31 (acc 32 VGPRs); feats once globally; 3-deep B
// register prefetch queue from frag-major W2f. Two barriers per chunk.
__global__ __launch_bounds__(512, 6) void kan_gemm2(
    const float* __restrict__ Hin, const bf16* __restrict__ W2f,
    float* __restrict__ Hp) {
  __shared__ __align__(16) bf16 As[64 * 232];  // 29696 B
  const int t = threadIdx.x;
  const int w = t >> 6, lane = t & 63, quad = lane >> 4, lr = lane & 15;
  const int m0 = blockIdx.x * 64;
  const int z = blockIdx.y;
  const int ej = t & 15, er0 = (t >> 4) & 31;
  const int foff = lr * 32 + quad * 8;
  f32x4_t acc[4][2];
#pragma unroll
  for (int m = 0; m < 4; ++m) {
    acc[m][0] = (f32x4_t){0.f, 0.f, 0.f, 0.f};
    acc[m][1] = (f32x4_t){0.f, 0.f, 0.f, 0.f};
  }
  const float* hp = Hin + (size_t)(m0 + er0) * 256 + z * 64 + ej;
  // B prefetch queue: frag-pair stride per K-step = 16 frags = 8192 elements
  const bf16* wbase = W2f + ((size_t)(z * 28 * 16 + w * 2)) * 512 + foff;
  bf16x8_t p0[3], p1[3];
#pragma unroll
  for (int s = 0; s < 3; ++s) {
    p0[s] = *(const bf16x8_t*)(wbase + (size_t)s * 8192);
    p1[s] = *(const bf16x8_t*)(wbase + (size_t)s * 8192 + 512);
  }
#pragma unroll
  for (int kcl = 0; kcl < 4; ++kcl) {
    kan_feats28(As + er0 * 232 + ej * 14, hp[kcl * 16]);
    kan_feats28(As + (er0 + 32) * 232 + ej * 14, hp[32 * 256 + kcl * 16]);
    __syncthreads();  // feats visible to all waves
#pragma unroll
    for (int ks = 0; ks < 7; ++ks) {
      const int step = kcl * 7 + ks;
      const int slot = step % 3;
      bf16x8_t b0 = p0[slot], b1 = p1[slot];
      if (step + 3 < 28) {
        p0[slot] = *(const bf16x8_t*)(wbase + (size_t)(step + 3) * 8192);
        p1[slot] = *(const bf16x8_t*)(wbase + (size_t)(step + 3) * 8192 + 512);
      }
#pragma unroll
      for (int m = 0; m < 4; ++m) {
        bf16x8_t a = *(const bf16x8_t*)(As + (m * 16 + lr) * 232 + ks * 32 + quad * 8);
        acc[m][0] = __builtin_amdgcn_mfma_f32_16x16x32_bf16(a, b0, acc[m][0], 0, 0, 0);
        acc[m][1] = __builtin_amdgcn_mfma_f32_16x16x32_bf16(a, b1, acc[m][1], 0, 0, 0);
      }
    }
    __syncthreads();  // all reads done before next chunk's feats overwrite
  }
  float* Hpz = Hp + (size_t)z * (8192 * 256);
  const int c0 = w * 32 + lr;
#pragma unroll
  for (int m = 0; m < 4; ++m)
#pragma unroll
    for (int r = 0; r < 4; ++r) {
      const size_t row = (size_t)(m0 + m * 16 + quad * 4 + r);
      Hpz[row * 256 + c0] = acc[m][0][r];
      Hpz[row * 256 + c0 + 16] = acc[m][1][r];
    }
}

// Fused layer 3: reduces the 4 layer-2 partials (+b2) inline, B register-direct
// from frag-major W3f (broadcast, L2-resident). Split-K z=8 -> 1024 blocks;
// launch_bounds(256,8) -> VGPR<=64 so 4+ blocks/CU pack.
__global__ __launch_bounds__(256, 8) void kan_gemm3(
    const float* __restrict__ Hp, const float* __restrict__ b2,
    const bf16* __restrict__ W3f, float* __restrict__ part) {
  __shared__ __align__(16) bf16 As[64 * 232];
  const int t = threadIdx.x;
  const int wv = t >> 6, lane = t & 63, quad = lane >> 4, lr = lane & 15;
  const int m0 = blockIdx.x * 64;
  const int z = blockIdx.y;  // 0..7
  const int ej = t & 15, er0 = t >> 4;
  const int foff = lr * 32 + quad * 8;
  f32x4_t acc = {0.f, 0.f, 0.f, 0.f};
#pragma unroll
  for (int kcl = 0; kcl < 2; ++kcl) {
    const int kc = z * 2 + kcl;
    const float bc = b2[kc * 16 + ej];
    const float* hp = Hp + (size_t)(m0 + er0) * 256 + kc * 16 + ej;
    if (kcl) __syncthreads();  // all waves done reading As before overwrite
#pragma unroll
    for (int e = 0; e < 4; ++e) {
      const size_t idx = (size_t)e * 16 * 256;
      float h = hp[idx] + hp[idx + 2097152] + hp[idx + 4194304] + hp[idx + 6291456] + bc;
      kan_feats28(As + (er0 + 16 * e) * 232 + ej * 14, h);
    }
    __syncthreads();
#pragma unroll
    for (int ks = 0; ks < 7; ++ks) {
      bf16x8_t b = *(const bf16x8_t*)(W3f + (size_t)(kc * 7 + ks) * 512 + foff);
      bf16x8_t a = *(const bf16x8_t*)(As + (wv * 16 + lr) * 232 + ks * 32 + quad * 8);
      acc = __builtin_amdgcn_mfma_f32_16x16x32_bf16(a, b, acc, 0, 0, 0);
    }
  }
#pragma unroll
  for (int r = 0; r < 4; ++r)
    part[(size_t)z * 131072 + (size_t)lr * 8192 + (m0 + wv * 16 + quad * 4 + r)] = acc[r];
}

// Reduce 8 split-K partials + bias, log_softmax over 10 classes.
__global__ __launch_bounds__(256) void lsm(const float* __restrict__ part,
                                           const float* __restrict__ b3,
                                           float* __restrict__ out) {
  const int row = blockIdx.x * 256 + threadIdx.x;
  float v[10];
#pragma unroll
  for (int o = 0; o < 10; ++o) {
    float s = b3[o];
#pragma unroll
    for (int kc = 0; kc < 8; ++kc) s += part[(size_t)kc * 131072 + (size_t)o * 8192 + row];
    v[o] = s;
  }
  float m = v[0];
#pragma unroll
  for (int o = 1; o < 10; ++o) m = fmaxf(m, v[o]);
  float se = 0.f;
#pragma unroll
  for (int o = 0; o < 10; ++o) se += expf(v[o] - m);
  const float l = m + logf(se);
#pragma unroll
  for (int o = 0; o < 10; ++o) out[(size_t)row * 10 + o] = v[o] - l;
}

extern "C" void kernel_launch(void* const* d_in, const int* in_sizes, int n_in,
                              void* d_out, int out_size, void* d_ws, size_t ws_size,
                              hipStream_t stream) {
  const float* x = (const float*)d_in[0];
  const float* coef1 = (const float*)d_in[1];
  const float* sb1 = (const float*)d_in[2];
  const float* sp1 = (const float*)d_in[3];
  const float* b1 = (const float*)d_in[4];
  const float* coef2 = (const float*)d_in[5];
  const float* sb2 = (const float*)d_in[6];
  const float* sp2 = (const float*)d_in[7];
  const float* b2 = (const float*)d_in[8];
  const float* coef3 = (const float*)d_in[9];
  const float* sb3 = (const float*)d_in[10];
  const float* sp3 = (const float*)d_in[11];
  const float* b3 = (const float*)d_in[12];
  float* out = (float*)d_out;

  char* ws = (char*)d_ws;
  size_t off = 0;
  bf16* A1 = (bf16*)(ws + off);    off += 11534336;  // 8192*704*2
  bf16* W1t = (bf16*)(ws + off);   off += 360448;    // 256*704*2
  bf16* W2f = (bf16*)(ws + off);   off += 1835008;   // 256*3584*2 (frag-major)
  bf16* W3f = (bf16*)(ws + off);   off += 114688;    // 16*3584*2 (frag-major)
  float* H1 = (float*)(ws + off);  off += 8388608;   // 8192*256*4
  float* Hp = (float*)(ws + off);  off += 33554432;  // 4 x 8192*256*4
  float* part = (float*)(ws + off); off += 4194304;  // 8*16*8192*4

  prep_pool<<<2610, 256, 0, stream>>>(x, coef1, sb1, sp1, coef2, sb2, sp2,
                                      coef3, sb3, sp3, A1, W1t, W2f, W3f);
  gemm1s<<<dim3(4, 128), 256, 0, stream>>>(A1, W1t, b1, H1);
  kan_gemm2<<<dim3(128, 4), 512, 0, stream>>>(H1, W2f, Hp);
  kan_gemm3<<<dim3(128, 8), 256, 0, stream>>>(Hp, b2, W3f, part);
  lsm<<<32, 256, 0, stream>>>(part, b3, out);
}

// Round 10
// 141.065 us; speedup vs baseline: 1.0382x; 1.0328x over previous
//
#include <hip/hip_runtime.h>
#include <hip/hip_bf16.h>

typedef __bf16 bf16x8_t __attribute__((ext_vector_type(8)));
typedef float f32x4_t __attribute__((ext_vector_type(4)));
using bf16 = __hip_bfloat16;

__device__ __forceinline__ unsigned short f2bf_bits(float v) {
  __hip_bfloat16 h = __float2bfloat16(v);
  return *reinterpret_cast<unsigned short*>(&h);
}

// mish(x) = x*tanh(softplus(x)) = x*n/(n+2) with n = e^x*(e^x+2).
__device__ __forceinline__ float mish_f(float x) {
  float z = __expf(x);
  float n = z * (z + 2.0f);
  float m = x * n / (n + 2.0f);
  return (x > 10.0f) ? x : m;
}

// 13 cubic B-spline basis values (grid 10, k=3, [-2,2]) + mish -> 28B LDS region.
__device__ __forceinline__ void kan_feats28(bf16* dst, float x) {
  unsigned int* d32 = (unsigned int*)dst;
#pragma unroll
  for (int d = 0; d < 7; ++d) d32[d] = 0u;
  float t = (x + 3.2f) * 2.5f;
  if (t >= 0.0f && t < 16.0f) {
    float tf = floorf(t);
    int c = (int)tf;
    float u = t - tf;
    float um = 1.0f - u;
    float u2 = u * u, u3 = u2 * u;
    const float s6 = 1.0f / 6.0f;
    float w0 = um * um * um * s6;
    float w1 = (3.0f * u3 - 6.0f * u2 + 4.0f) * s6;
    float w2 = (-3.0f * u3 + 3.0f * u2 + 3.0f * u + 1.0f) * s6;
    float w3 = u3 * s6;
    int j0 = c - 3;
    if (j0 >= 0)               dst[j0]     = __float2bfloat16(w0);
    if (j0 >= -1 && j0 <= 11)  dst[j0 + 1] = __float2bfloat16(w1);
    if (j0 >= -2 && j0 <= 10)  dst[j0 + 2] = __float2bfloat16(w2);
    if (j0 <= 9)               dst[j0 + 3] = __float2bfloat16(w3);
  }
  dst[13] = __float2bfloat16(mish_f(x));
}

// Builds W1f, W2f, W3f — ALL MFMA-fragment-major. Frag s (global k-frag of 32)
// x ntg (group of 16 N-rows): 512 elements (1KB); element (n,quad,el) at
// (s*16+ntg)*512 + n*32 + quad*8 + el. k'=i*14+2d even -> bf16 pairs = dwords.
__global__ __launch_bounds__(256) void prep_all(
    const float* __restrict__ c1, const float* __restrict__ sb1, const float* __restrict__ sp1,
    const float* __restrict__ c2, const float* __restrict__ sb2, const float* __restrict__ sp2,
    const float* __restrict__ c3, const float* __restrict__ sb3, const float* __restrict__ sp3,
    bf16* __restrict__ W1f, bf16* __restrict__ W2f, bf16* __restrict__ W3f) {
  const int b = blockIdx.x, o = threadIdx.x;
  float vals[14];
  const int ntg = o >> 4, lrr = o & 15;
  if (b < 49) {
    const int i = b;
    const size_t io = (size_t)i * 256 + o;
    const float spv = sp1[io];
#pragma unroll
    for (int r = 0; r < 13; ++r) vals[r] = c1[io * 13 + r] * spv;
    vals[13] = sb1[io];
#pragma unroll
    for (int d = 0; d < 7; ++d) {
      const int k2 = i * 14 + 2 * d;
      const int s = k2 >> 5, r2 = k2 & 31;
      const size_t off = ((size_t)(s * 16 + ntg)) * 512 + lrr * 32 + (r2 >> 3) * 8 + (r2 & 7);
      *(unsigned int*)(W1f + off) = (unsigned int)f2bf_bits(vals[2 * d]) |
                                    ((unsigned int)f2bf_bits(vals[2 * d + 1]) << 16);
    }
  } else if (b == 49) {
    // zero W1f K-pad 686..703 (k-frag 21, elements 14..31)
#pragma unroll
    for (int d = 0; d < 9; ++d) {
      const int k2 = 686 + 2 * d;
      const int r2 = k2 & 31;
      *(unsigned int*)(W1f + ((size_t)(21 * 16 + ntg)) * 512 + lrr * 32 + (r2 >> 3) * 8 + (r2 & 7)) = 0u;
    }
  } else if (b < 306) {
    const int i = b - 50;
    const size_t io = (size_t)i * 256 + o;
    const float spv = sp2[io];
#pragma unroll
    for (int r = 0; r < 13; ++r) vals[r] = c2[io * 13 + r] * spv;
    vals[13] = sb2[io];
#pragma unroll
    for (int d = 0; d < 7; ++d) {
      const int k2 = i * 14 + 2 * d;
      const int s = k2 >> 5, r2 = k2 & 31;
      const size_t off = ((size_t)(s * 16 + ntg)) * 512 + lrr * 32 + (r2 >> 3) * 8 + (r2 & 7);
      *(unsigned int*)(W2f + off) = (unsigned int)f2bf_bits(vals[2 * d]) |
                                    ((unsigned int)f2bf_bits(vals[2 * d + 1]) << 16);
    }
  } else {
    const int i = b - 306;
    if (o < 10) {
      const size_t io = (size_t)i * 10 + o;
      const float spv = sp3[io];
#pragma unroll
      for (int r = 0; r < 13; ++r) vals[r] = c3[io * 13 + r] * spv;
      vals[13] = sb3[io];
#pragma unroll
      for (int d = 0; d < 7; ++d) {
        const int k2 = i * 14 + 2 * d;
        const int s = k2 >> 5, r2 = k2 & 31;
        const size_t off = (size_t)s * 512 + o * 32 + (r2 >> 3) * 8 + (r2 & 7);
        *(unsigned int*)(W3f + off) = (unsigned int)f2bf_bits(vals[2 * d]) |
                                      ((unsigned int)f2bf_bits(vals[2 * d + 1]) << 16);
      }
    } else if (o < 16) {
#pragma unroll
      for (int d = 0; d < 7; ++d) {
        const int k2 = i * 14 + 2 * d;
        const int s = k2 >> 5, r2 = k2 & 31;
        *(unsigned int*)(W3f + (size_t)s * 512 + o * 32 + (r2 >> 3) * 8 + (r2 & 7)) = 0u;
      }
    }
  }
}

// Whole-network megakernel: 256 blocks x 512 threads; block b owns rows
// b*32..+31 end-to-end (pool -> L1 -> L2 -> L3 -> log_softmax). All weights
// register-direct from frag-major L2-resident buffers; activations never
// leave LDS. Chunk-dbuf A-tiles (232-stride, proven), depth-4 B queue (R7).
__global__ __launch_bounds__(512, 2) void meganet(
    const float* __restrict__ x, const bf16* __restrict__ W1f,
    const bf16* __restrict__ W2f, const bf16* __restrict__ W3f,
    const float* __restrict__ b1, const float* __restrict__ b2,
    const float* __restrict__ b3, float* __restrict__ out) {
  __shared__ __align__(16) char lds[120320];
  float* const xs = (float*)lds;             // [0,50176) phase A only
  float* const P = (float*)(lds + 50176);    // [50176,57344) 32x56 f32, A->B
  float* const Hs1 = (float*)lds;            // [0,33280) 32x260 f32, B->C
  bf16* const Ach0 = (bf16*)(lds + 57344);   // 14848 (32x232 bf16)
  bf16* const Ach1 = (bf16*)(lds + 72192);   // 14848
  float* const Hs2 = (float*)(lds + 87040);  // [87040,120320) 32x260, C->E
  float* const Red = (float*)lds;            // [0,14336) E tail
  float* const V = (float*)(lds + 14336);    // [14336,16384)

  const int t = threadIdx.x;
  const int w = t >> 6, lane = t & 63, quad = lane >> 4, lr = lane & 15;
  const int tr = t >> 4, ej = t & 15;  // feats coords: row tr (0..31), input ej
  const int r0 = blockIdx.x * 32;
  const int ntg0 = w * 2;
  const int foff = lr * 32 + quad * 8;

  // ---- Phase A: pool 32 images -> P[32][49] (stride 56) ----
  for (int h = 0; h < 2; ++h) {
    const float4* src = (const float4*)x + (size_t)(r0 + h * 16) * 196;
    float4* xd = (float4*)xs;
#pragma unroll
    for (int l = 0; l < 7; ++l) {
      const int idx = t + l * 512;
      if (idx < 3136) xd[idx] = src[idx];
    }
    __syncthreads();
    for (int task = t; task < 784; task += 512) {
      const int img = task / 49, p = task - img * 49;
      const int oh = p / 7, ow = p - oh * 7;
      const float* xi = xs + img * 784 + oh * 112 + ow * 4;
      float s = 0.f;
#pragma unroll
      for (int rr = 0; rr < 4; ++rr)
#pragma unroll
        for (int cc = 0; cc < 4; ++cc) s += xi[rr * 28 + cc];
      P[(h * 16 + img) * 56 + p] = s * (1.0f / 16.0f);
    }
    __syncthreads();
  }

  // ---- Phase B: layer-1 GEMM, K=704 (22 k-frags: chunks 7,7,7,1) ----
  f32x4_t acc1[2][2];
#pragma unroll
  for (int m = 0; m < 2; ++m)
#pragma unroll
    for (int n = 0; n < 2; ++n) acc1[m][n] = (f32x4_t){0.f, 0.f, 0.f, 0.f};
  bf16x8_t qa[4], qb[4];
#pragma unroll
  for (int s = 0; s < 4; ++s) {
    qa[s] = *(const bf16x8_t*)(W1f + (size_t)(s * 16 + ntg0) * 512 + foff);
    qb[s] = *(const bf16x8_t*)(W1f + (size_t)(s * 16 + ntg0 + 1) * 512 + foff);
  }
  kan_feats28(Ach0 + tr * 232 + ej * 14, P[tr * 56 + ej]);
  __syncthreads();
#pragma unroll
  for (int c = 0; c < 4; ++c) {
    const bf16* const Ac = (c & 1) ? Ach1 : Ach0;
    bf16* const An = (c & 1) ? Ach0 : Ach1;
    const int nks = (c < 3) ? 7 : 1;
#pragma unroll
    for (int ks = 0; ks < 7; ++ks) {
      if (ks >= nks) continue;
      const int kk = c * 7 + ks;
      const int sl = kk & 3;
      bf16x8_t bb0 = qa[sl], bb1 = qb[sl];
      if (kk + 4 < 22) {
        qa[sl] = *(const bf16x8_t*)(W1f + (size_t)((kk + 4) * 16 + ntg0) * 512 + foff);
        qb[sl] = *(const bf16x8_t*)(W1f + (size_t)((kk + 4) * 16 + ntg0 + 1) * 512 + foff);
      }
#pragma unroll
      for (int m = 0; m < 2; ++m) {
        bf16x8_t a = *(const bf16x8_t*)(Ac + (m * 16 + lr) * 232 + ks * 32 + quad * 8);
        acc1[m][0] = __builtin_amdgcn_mfma_f32_16x16x32_bf16(a, bb0, acc1[m][0], 0, 0, 0);
        acc1[m][1] = __builtin_amdgcn_mfma_f32_16x16x32_bf16(a, bb1, acc1[m][1], 0, 0, 0);
      }
    }
    if (c < 2) {
      kan_feats28(An + tr * 232 + ej * 14, P[tr * 56 + (c + 1) * 16 + ej]);
    } else if (c == 2) {
      if (ej == 0) kan_feats28(An + tr * 232, P[tr * 56 + 48]);
      else if (ej == 1) {
        unsigned int* z = (unsigned int*)(An + tr * 232 + 14);
#pragma unroll
        for (int d = 0; d < 9; ++d) z[d] = 0u;  // pad k 686..703
      }
    }
    __syncthreads();
  }
  // H1 = acc1 + b1 -> Hs1 (stride 260)
#pragma unroll
  for (int m = 0; m < 2; ++m)
#pragma unroll
    for (int n = 0; n < 2; ++n) {
      const int col = w * 32 + n * 16 + lr;
      const float bn = b1[col];
#pragma unroll
      for (int r = 0; r < 4; ++r)
        Hs1[(m * 16 + quad * 4 + r) * 260 + col] = acc1[m][n][r] + bn;
    }
  __syncthreads();

  // ---- Phase C: layer-2 GEMM, K=3584 (16 chunks x 7 k-frags) ----
  f32x4_t acc2[2][2];
#pragma unroll
  for (int m = 0; m < 2; ++m)
#pragma unroll
    for (int n = 0; n < 2; ++n) acc2[m][n] = (f32x4_t){0.f, 0.f, 0.f, 0.f};
#pragma unroll
  for (int s = 0; s < 4; ++s) {
    qa[s] = *(const bf16x8_t*)(W2f + (size_t)(s * 16 + ntg0) * 512 + foff);
    qb[s] = *(const bf16x8_t*)(W2f + (size_t)(s * 16 + ntg0 + 1) * 512 + foff);
  }
  kan_feats28(Ach0 + tr * 232 + ej * 14, Hs1[tr * 260 + ej]);
  __syncthreads();
#pragma unroll
  for (int c = 0; c < 16; ++c) {
    const bf16* const Ac = (c & 1) ? Ach1 : Ach0;
    bf16* const An = (c & 1) ? Ach0 : Ach1;
#pragma unroll
    for (int ks = 0; ks < 7; ++ks) {
      const int kk = c * 7 + ks;
      const int sl = kk & 3;
      bf16x8_t bb0 = qa[sl], bb1 = qb[sl];
      if (kk + 4 < 112) {
        qa[sl] = *(const bf16x8_t*)(W2f + (size_t)((kk + 4) * 16 + ntg0) * 512 + foff);
        qb[sl] = *(const bf16x8_t*)(W2f + (size_t)((kk + 4) * 16 + ntg0 + 1) * 512 + foff);
      }
#pragma unroll
      for (int m = 0; m < 2; ++m) {
        bf16x8_t a = *(const bf16x8_t*)(Ac + (m * 16 + lr) * 232 + ks * 32 + quad * 8);
        acc2[m][0] = __builtin_amdgcn_mfma_f32_16x16x32_bf16(a, bb0, acc2[m][0], 0, 0, 0);
        acc2[m][1] = __builtin_amdgcn_mfma_f32_16x16x32_bf16(a, bb1, acc2[m][1], 0, 0, 0);
      }
    }
    if (c < 15)
      kan_feats28(An + tr * 232 + ej * 14, Hs1[tr * 260 + (c + 1) * 16 + ej]);
    __syncthreads();
  }
  // H2 = acc2 + b2 -> Hs2
#pragma unroll
  for (int m = 0; m < 2; ++m)
#pragma unroll
    for (int n = 0; n < 2; ++n) {
      const int col = w * 32 + n * 16 + lr;
      const float bn = b2[col];
#pragma unroll
      for (int r = 0; r < 4; ++r)
        Hs2[(m * 16 + quad * 4 + r) * 260 + col] = acc2[m][n][r] + bn;
    }
  __syncthreads();

  // ---- Phase E: layer-3 GEMM (N=16, 10 real), waves 0..6 split ks ----
  f32x4_t acc3[2];
  acc3[0] = (f32x4_t){0.f, 0.f, 0.f, 0.f};
  acc3[1] = acc3[0];
  bf16x8_t w3q[2];
  if (w < 7) {
    w3q[0] = *(const bf16x8_t*)(W3f + (size_t)(0 * 7 + w) * 512 + foff);
    w3q[1] = *(const bf16x8_t*)(W3f + (size_t)(1 * 7 + w) * 512 + foff);
  }
  kan_feats28(Ach0 + tr * 232 + ej * 14, Hs2[tr * 260 + ej]);
  __syncthreads();
#pragma unroll
  for (int c = 0; c < 16; ++c) {
    const bf16* const Ac = (c & 1) ? Ach1 : Ach0;
    bf16* const An = (c & 1) ? Ach0 : Ach1;
    if (w < 7) {
      bf16x8_t bb = w3q[c & 1];
      if (c + 2 < 16)
        w3q[c & 1] = *(const bf16x8_t*)(W3f + (size_t)((c + 2) * 7 + w) * 512 + foff);
#pragma unroll
      for (int m = 0; m < 2; ++m) {
        bf16x8_t a = *(const bf16x8_t*)(Ac + (m * 16 + lr) * 232 + w * 32 + quad * 8);
        acc3[m] = __builtin_amdgcn_mfma_f32_16x16x32_bf16(a, bb, acc3[m], 0, 0, 0);
      }
    }
    if (c < 15)
      kan_feats28(An + tr * 232 + ej * 14, Hs2[tr * 260 + (c + 1) * 16 + ej]);
    __syncthreads();
  }
  if (w < 7) {
#pragma unroll
    for (int m = 0; m < 2; ++m)
#pragma unroll
      for (int r = 0; r < 4; ++r)
        Red[w * 512 + (m * 16 + quad * 4 + r) * 16 + lr] = acc3[m][r];
  }
  __syncthreads();
  {
    float s = (ej < 10) ? b3[ej] : 0.f;
#pragma unroll
    for (int wv = 0; wv < 7; ++wv) s += Red[wv * 512 + tr * 16 + ej];
    V[tr * 16 + ej] = s;
  }
  __syncthreads();
  if (t < 32) {
    float vv[10];
#pragma unroll
    for (int o = 0; o < 10; ++o) vv[o] = V[t * 16 + o];
    float mx = vv[0];
#pragma unroll
    for (int o = 1; o < 10; ++o) mx = fmaxf(mx, vv[o]);
    float se = 0.f;
#pragma unroll
    for (int o = 0; o < 10; ++o) se += expf(vv[o] - mx);
    const float l = mx + logf(se);
#pragma unroll
    for (int o = 0; o < 10; ++o) out[(size_t)(r0 + t) * 10 + o] = vv[o] - l;
  }
}

extern "C" void kernel_launch(void* const* d_in, const int* in_sizes, int n_in,
                              void* d_out, int out_size, void* d_ws, size_t ws_size,
                              hipStream_t stream) {
  const float* x = (const float*)d_in[0];
  const float* coef1 = (const float*)d_in[1];
  const float* sb1 = (const float*)d_in[2];
  const float* sp1 = (const float*)d_in[3];
  const float* b1 = (const float*)d_in[4];
  const float* coef2 = (const float*)d_in[5];
  const float* sb2 = (const float*)d_in[6];
  const float* sp2 = (const float*)d_in[7];
  const float* b2 = (const float*)d_in[8];
  const float* coef3 = (const float*)d_in[9];
  const float* sb3 = (const float*)d_in[10];
  const float* sp3 = (const float*)d_in[11];
  const float* b3 = (const float*)d_in[12];
  float* out = (float*)d_out;

  char* ws = (char*)d_ws;
  bf16* W1f = (bf16*)ws;              // 22 frags x 16 ntg x 1KB = 360448 B
  bf16* W2f = (bf16*)(ws + 360448);   // 112 x 16 x 1KB = 1835008 B
  bf16* W3f = (bf16*)(ws + 2195456);  // 112 x 1KB = 114688 B

  prep_all<<<562, 256, 0, stream>>>(coef1, sb1, sp1, coef2, sb2, sp2,
                                    coef3, sb3, sp3, W1f, W2f, W3f);
  meganet<<<256, 512, 0, stream>>>(x, W1f, W2f, W3f, b1, b2, b3, out);
}

// Round 11
// 139.709 us; speedup vs baseline: 1.0483x; 1.0097x over previous
//
#include <hip/hip_runtime.h>
#include <hip/hip_bf16.h>

typedef __bf16 bf16x8_t __attribute__((ext_vector_type(8)));
typedef float f32x4_t __attribute__((ext_vector_type(4)));
using bf16 = __hip_bfloat16;

__device__ __forceinline__ unsigned short f2bf_bits(float v) {
  __hip_bfloat16 h = __float2bfloat16(v);
  return *reinterpret_cast<unsigned short*>(&h);
}

// mish(x) = x*tanh(softplus(x)) = x*n/(n+2) with n = e^x*(e^x+2).
__device__ __forceinline__ float mish_f(float x) {
  float z = __expf(x);
  float n = z * (z + 2.0f);
  float m = x * n / (n + 2.0f);
  return (x > 10.0f) ? x : m;
}

// 13 cubic B-spline basis values (grid 10, k=3, [-2,2]) + mish -> 28B LDS region.
__device__ __forceinline__ void kan_feats28(bf16* dst, float x) {
  unsigned int* d32 = (unsigned int*)dst;
#pragma unroll
  for (int d = 0; d < 7; ++d) d32[d] = 0u;
  float t = (x + 3.2f) * 2.5f;
  if (t >= 0.0f && t < 16.0f) {
    float tf = floorf(t);
    int c = (int)tf;
    float u = t - tf;
    float um = 1.0f - u;
    float u2 = u * u, u3 = u2 * u;
    const float s6 = 1.0f / 6.0f;
    float w0 = um * um * um * s6;
    float w1 = (3.0f * u3 - 6.0f * u2 + 4.0f) * s6;
    float w2 = (-3.0f * u3 + 3.0f * u2 + 3.0f * u + 1.0f) * s6;
    float w3 = u3 * s6;
    int j0 = c - 3;
    if (j0 >= 0)               dst[j0]     = __float2bfloat16(w0);
    if (j0 >= -1 && j0 <= 11)  dst[j0 + 1] = __float2bfloat16(w1);
    if (j0 >= -2 && j0 <= 10)  dst[j0 + 2] = __float2bfloat16(w2);
    if (j0 <= 9)               dst[j0 + 3] = __float2bfloat16(w3);
  }
  dst[13] = __float2bfloat16(mish_f(x));
}

// Builds W1f, W2f, W3f — ALL MFMA-fragment-major. Frag s (global k-frag of 32)
// x ntg (group of 16 N-rows): 512 elements (1KB); element (n,quad,el) at
// (s*16+ntg)*512 + n*32 + quad*8 + el. k'=i*14+2d even -> bf16 pairs = dwords.
__global__ __launch_bounds__(256) void prep_all(
    const float* __restrict__ c1, const float* __restrict__ sb1, const float* __restrict__ sp1,
    const float* __restrict__ c2, const float* __restrict__ sb2, const float* __restrict__ sp2,
    const float* __restrict__ c3, const float* __restrict__ sb3, const float* __restrict__ sp3,
    bf16* __restrict__ W1f, bf16* __restrict__ W2f, bf16* __restrict__ W3f) {
  const int b = blockIdx.x, o = threadIdx.x;
  float vals[14];
  const int ntg = o >> 4, lrr = o & 15;
  if (b < 49) {
    const int i = b;
    const size_t io = (size_t)i * 256 + o;
    const float spv = sp1[io];
#pragma unroll
    for (int r = 0; r < 13; ++r) vals[r] = c1[io * 13 + r] * spv;
    vals[13] = sb1[io];
#pragma unroll
    for (int d = 0; d < 7; ++d) {
      const int k2 = i * 14 + 2 * d;
      const int s = k2 >> 5, r2 = k2 & 31;
      const size_t off = ((size_t)(s * 16 + ntg)) * 512 + lrr * 32 + (r2 >> 3) * 8 + (r2 & 7);
      *(unsigned int*)(W1f + off) = (unsigned int)f2bf_bits(vals[2 * d]) |
                                    ((unsigned int)f2bf_bits(vals[2 * d + 1]) << 16);
    }
  } else if (b == 49) {
    // zero W1f K-pad 686..703 (k-frag 21, elements 14..31)
#pragma unroll
    for (int d = 0; d < 9; ++d) {
      const int k2 = 686 + 2 * d;
      const int r2 = k2 & 31;
      *(unsigned int*)(W1f + ((size_t)(21 * 16 + ntg)) * 512 + lrr * 32 + (r2 >> 3) * 8 + (r2 & 7)) = 0u;
    }
  } else if (b < 306) {
    const int i = b - 50;
    const size_t io = (size_t)i * 256 + o;
    const float spv = sp2[io];
#pragma unroll
    for (int r = 0; r < 13; ++r) vals[r] = c2[io * 13 + r] * spv;
    vals[13] = sb2[io];
#pragma unroll
    for (int d = 0; d < 7; ++d) {
      const int k2 = i * 14 + 2 * d;
      const int s = k2 >> 5, r2 = k2 & 31;
      const size_t off = ((size_t)(s * 16 + ntg)) * 512 + lrr * 32 + (r2 >> 3) * 8 + (r2 & 7);
      *(unsigned int*)(W2f + off) = (unsigned int)f2bf_bits(vals[2 * d]) |
                                    ((unsigned int)f2bf_bits(vals[2 * d + 1]) << 16);
    }
  } else {
    const int i = b - 306;
    if (o < 10) {
      const size_t io = (size_t)i * 10 + o;
      const float spv = sp3[io];
#pragma unroll
      for (int r = 0; r < 13; ++r) vals[r] = c3[io * 13 + r] * spv;
      vals[13] = sb3[io];
#pragma unroll
      for (int d = 0; d < 7; ++d) {
        const int k2 = i * 14 + 2 * d;
        const int s = k2 >> 5, r2 = k2 & 31;
        const size_t off = (size_t)s * 512 + o * 32 + (r2 >> 3) * 8 + (r2 & 7);
        *(unsigned int*)(W3f + off) = (unsigned int)f2bf_bits(vals[2 * d]) |
                                      ((unsigned int)f2bf_bits(vals[2 * d + 1]) << 16);
      }
    } else if (o < 16) {
#pragma unroll
      for (int d = 0; d < 7; ++d) {
        const int k2 = i * 14 + 2 * d;
        const int s = k2 >> 5, r2 = k2 & 31;
        *(unsigned int*)(W3f + (size_t)s * 512 + o * 32 + (r2 >> 3) * 8 + (r2 & 7)) = 0u;
      }
    }
  }
}

// Whole-network megakernel v2: 256 blocks x 1024 threads (16 waves = 4/SIMD).
// Block owns rows b*32..+31 end-to-end. Wave w owns cols w*16..+15 (acc 2x1
// frags = 8 VGPRs). Feats by waves 0..7 (t<512); waves 8..15 pure MFMA co-
// scheduled. Hs TRANSPOSED [col][36] f32: feats read bank=4ej+tr (2-way free),
// epilogue b128 writes at 8-deep floor. H2 overwrites H1 region. LDS 73728.
__global__ __launch_bounds__(1024, 4) void meganet(
    const float* __restrict__ x, const bf16* __restrict__ W1f,
    const bf16* __restrict__ W2f, const bf16* __restrict__ W3f,
    const float* __restrict__ b1, const float* __restrict__ b2,
    const float* __restrict__ b3, float* __restrict__ out) {
  __shared__ __align__(16) char lds[73728];
  float* const Hs = (float*)lds;             // [256][36] f32 transposed
  bf16* const Ach0 = (bf16*)(lds + 36864);   // [32][232] bf16
  bf16* const Ach1 = (bf16*)(lds + 51712);
  float* const P = (float*)(lds + 66560);    // [32][56] f32
  float* const xs = (float*)lds;             // phase A only (50176)
  float* const Red = (float*)(lds + 36864);  // 14x256 f32 (E tail)
  float* const V = (float*)(lds + 51712);    // 32x16 f32

  const int t = threadIdx.x;
  const int w = t >> 6, lane = t & 63, quad = lane >> 4, lr = lane & 15;
  const int tr = t >> 4, ej = t & 15;  // eval coords (valid t<512)
  const int r0 = blockIdx.x * 32;
  const int foff = lr * 32 + quad * 8;

  // ---- Phase A: pool 32 images -> P[32][56] ----
  for (int h = 0; h < 2; ++h) {
    const float4* src = (const float4*)x + (size_t)(r0 + h * 16) * 196;
    float4* xd = (float4*)xs;
#pragma unroll
    for (int l = 0; l < 4; ++l) {
      const int idx = t + l * 1024;
      if (idx < 3136) xd[idx] = src[idx];
    }
    __syncthreads();
    if (t < 784) {
      const int img = t / 49, p = t - img * 49;
      const int oh = p / 7, ow = p - oh * 7;
      const float* xi = xs + img * 784 + oh * 112 + ow * 4;
      float s = 0.f;
#pragma unroll
      for (int rr = 0; rr < 4; ++rr)
#pragma unroll
        for (int cc = 0; cc < 4; ++cc) s += xi[rr * 28 + cc];
      P[(h * 16 + img) * 56 + p] = s * (1.0f / 16.0f);
    }
    __syncthreads();
  }

  // ---- Phase B: layer-1, K=704 (22 k-frags: chunks 7,7,7,1) ----
  f32x4_t acc1[2];
  acc1[0] = (f32x4_t){0.f, 0.f, 0.f, 0.f};
  acc1[1] = acc1[0];
  bf16x8_t q[4];
#pragma unroll
  for (int s = 0; s < 4; ++s)
    q[s] = *(const bf16x8_t*)(W1f + (size_t)(s * 16 + w) * 512 + foff);
  if (t < 512) kan_feats28(Ach0 + tr * 232 + ej * 14, P[tr * 56 + ej]);
  __syncthreads();
#pragma unroll
  for (int c = 0; c < 4; ++c) {
    const bf16* const Ac = (c & 1) ? Ach1 : Ach0;
    bf16* const An = (c & 1) ? Ach0 : Ach1;
    const int nks = (c < 3) ? 7 : 1;
#pragma unroll
    for (int ks = 0; ks < 7; ++ks) {
      if (ks >= nks) continue;
      const int kk = c * 7 + ks;
      const int sl = kk & 3;
      bf16x8_t bb = q[sl];
      if (kk + 4 < 22)
        q[sl] = *(const bf16x8_t*)(W1f + (size_t)((kk + 4) * 16 + w) * 512 + foff);
#pragma unroll
      for (int m = 0; m < 2; ++m) {
        bf16x8_t a = *(const bf16x8_t*)(Ac + (m * 16 + lr) * 232 + ks * 32 + quad * 8);
        acc1[m] = __builtin_amdgcn_mfma_f32_16x16x32_bf16(a, bb, acc1[m], 0, 0, 0);
      }
    }
    if (t < 512) {
      if (c < 2) {
        kan_feats28(An + tr * 232 + ej * 14, P[tr * 56 + (c + 1) * 16 + ej]);
      } else if (c == 2) {
        if (ej == 0) kan_feats28(An + tr * 232, P[tr * 56 + 48]);
        else if (ej == 1) {
          unsigned int* z = (unsigned int*)(An + tr * 232 + 14);
#pragma unroll
          for (int d = 0; d < 9; ++d) z[d] = 0u;  // pad k 686..703
        }
      }
    }
    __syncthreads();
  }
  // H1 = acc1 + b1 -> Hs (transposed), b128 rows quad*4..+3
  {
    const int col = w * 16 + lr;
    const float bn = b1[col];
#pragma unroll
    for (int m = 0; m < 2; ++m) {
      f32x4_t v;
#pragma unroll
      for (int r = 0; r < 4; ++r) v[r] = acc1[m][r] + bn;
      *(f32x4_t*)(Hs + col * 36 + m * 16 + quad * 4) = v;
    }
  }
  __syncthreads();

  // ---- Phase C: layer-2, K=3584 (16 chunks x 7) ----
  f32x4_t acc2[2];
  acc2[0] = (f32x4_t){0.f, 0.f, 0.f, 0.f};
  acc2[1] = acc2[0];
#pragma unroll
  for (int s = 0; s < 4; ++s)
    q[s] = *(const bf16x8_t*)(W2f + (size_t)(s * 16 + w) * 512 + foff);
  if (t < 512) kan_feats28(Ach0 + tr * 232 + ej * 14, Hs[ej * 36 + tr]);
  __syncthreads();
#pragma unroll
  for (int c = 0; c < 16; ++c) {
    const bf16* const Ac = (c & 1) ? Ach1 : Ach0;
    bf16* const An = (c & 1) ? Ach0 : Ach1;
#pragma unroll
    for (int ks = 0; ks < 7; ++ks) {
      const int kk = c * 7 + ks;
      const int sl = kk & 3;
      bf16x8_t bb = q[sl];
      if (kk + 4 < 112)
        q[sl] = *(const bf16x8_t*)(W2f + (size_t)((kk + 4) * 16 + w) * 512 + foff);
#pragma unroll
      for (int m = 0; m < 2; ++m) {
        bf16x8_t a = *(const bf16x8_t*)(Ac + (m * 16 + lr) * 232 + ks * 32 + quad * 8);
        acc2[m] = __builtin_amdgcn_mfma_f32_16x16x32_bf16(a, bb, acc2[m], 0, 0, 0);
      }
    }
    if (t < 512 && c < 15)
      kan_feats28(An + tr * 232 + ej * 14, Hs[((c + 1) * 16 + ej) * 36 + tr]);
    __syncthreads();
  }
  // H2 = acc2 + b2 -> Hs (overwrite H1 region; H1 dead after chunk-15 feats)
  {
    const int col = w * 16 + lr;
    const float bn = b2[col];
#pragma unroll
    for (int m = 0; m < 2; ++m) {
      f32x4_t v;
#pragma unroll
      for (int r = 0; r < 4; ++r) v[r] = acc2[m][r] + bn;
      *(f32x4_t*)(Hs + col * 36 + m * 16 + quad * 4) = v;
    }
  }
  __syncthreads();

  // ---- Phase E: layer-3 (N=16, 10 real). Waves 0..13: (mh, ks3) split. ----
  f32x4_t acc3 = {0.f, 0.f, 0.f, 0.f};
  const int mh = w / 7, ks3 = w % 7;  // valid w<14
  bf16x8_t q3[2];
  if (w < 14) {
    q3[0] = *(const bf16x8_t*)(W3f + (size_t)ks3 * 512 + foff);
    q3[1] = *(const bf16x8_t*)(W3f + (size_t)(7 + ks3) * 512 + foff);
  }
  if (t < 512) kan_feats28(Ach0 + tr * 232 + ej * 14, Hs[ej * 36 + tr]);
  __syncthreads();
#pragma unroll
  for (int c = 0; c < 16; ++c) {
    const bf16* const Ac = (c & 1) ? Ach1 : Ach0;
    bf16* const An = (c & 1) ? Ach0 : Ach1;
    if (w < 14) {
      bf16x8_t bb = q3[c & 1];
      if (c + 2 < 16)
        q3[c & 1] = *(const bf16x8_t*)(W3f + (size_t)((c + 2) * 7 + ks3) * 512 + foff);
      bf16x8_t a = *(const bf16x8_t*)(Ac + (mh * 16 + lr) * 232 + ks3 * 32 + quad * 8);
      acc3 = __builtin_amdgcn_mfma_f32_16x16x32_bf16(a, bb, acc3, 0, 0, 0);
    }
    if (t < 512 && c < 15)
      kan_feats28(An + tr * 232 + ej * 14, Hs[((c + 1) * 16 + ej) * 36 + tr]);
    __syncthreads();
  }
  if (w < 14) {
#pragma unroll
    for (int r = 0; r < 4; ++r)
      Red[w * 256 + (quad * 4 + r) * 16 + lr] = acc3[r];
  }
  __syncthreads();
  if (t < 512 && tr < 32) {
    float s = (ej < 10) ? b3[ej] : 0.f;
    const int mh2 = tr >> 4, lrow = tr & 15;
#pragma unroll
    for (int ks = 0; ks < 7; ++ks) s += Red[(mh2 * 7 + ks) * 256 + lrow * 16 + ej];
    V[tr * 16 + ej] = s;
  }
  __syncthreads();
  if (t < 32) {
    float vv[10];
#pragma unroll
    for (int o = 0; o < 10; ++o) vv[o] = V[t * 16 + o];
    float mx = vv[0];
#pragma unroll
    for (int o = 1; o < 10; ++o) mx = fmaxf(mx, vv[o]);
    float se = 0.f;
#pragma unroll
    for (int o = 0; o < 10; ++o) se += expf(vv[o] - mx);
    const float l = mx + logf(se);
#pragma unroll
    for (int o = 0; o < 10; ++o) out[(size_t)(r0 + t) * 10 + o] = vv[o] - l;
  }
}

extern "C" void kernel_launch(void* const* d_in, const int* in_sizes, int n_in,
                              void* d_out, int out_size, void* d_ws, size_t ws_size,
                              hipStream_t stream) {
  const float* x = (const float*)d_in[0];
  const float* coef1 = (const float*)d_in[1];
  const float* sb1 = (const float*)d_in[2];
  const float* sp1 = (const float*)d_in[3];
  const float* b1 = (const float*)d_in[4];
  const float* coef2 = (const float*)d_in[5];
  const float* sb2 = (const float*)d_in[6];
  const float* sp2 = (const float*)d_in[7];
  const float* b2 = (const float*)d_in[8];
  const float* coef3 = (const float*)d_in[9];
  const float* sb3 = (const float*)d_in[10];
  const float* sp3 = (const float*)d_in[11];
  const float* b3 = (const float*)d_in[12];
  float* out = (float*)d_out;

  char* ws = (char*)d_ws;
  bf16* W1f = (bf16*)ws;              // 22 frags x 16 ntg x 1KB = 360448 B
  bf16* W2f = (bf16*)(ws + 360448);   // 112 x 16 x 1KB = 1835008 B
  bf16* W3f = (bf16*)(ws + 2195456);  // 112 x 1KB = 114688 B

  prep_all<<<562, 256, 0, stream>>>(coef1, sb1, sp1, coef2, sb2, sp2,
                                    coef3, sb3, sp3, W1f, W2f, W3f);
  meganet<<<256, 1024, 0, stream>>>(x, W1f, W2f, W3f, b1, b2, b3, out);
}